// Round 3
// baseline (105.108 us; speedup 1.0000x reference)
//
#include <hip/hip_runtime.h>
#include <math.h>

// TripletLoss semi-hard mining, N=512, D=512, C=64.
// For each ordered positive pair (j,a) [labels equal, j!=a]:
//   neg = min{ d[j][k] : lbl[k]!=lbl[j], d[j][k] > d[j][a] }
//         else max{ d[j][k] : lbl[k]!=lbl[j] } (0 if none)
//   loss += max(0, MARGIN + d[j][a] - neg);  out = loss / (numpos + 1e-8)
//
// v3: distance phase with NO LDS traffic — anchors in registers (stride-8
// column interleave), own rows streamed straight from global (L2-resident),
// 8x8 wave tile so the cross-lane reduce is 3 shuffle levels per 8 rows.

#define NN 512
#define TPB 512               // 8 waves; each wave computes 64 dist rows
#define NWAVES (TPB / 64)
#define MARGIN_F 0.2f

__global__ __launch_bounds__(TPB, 2) void triplet_main(
    const int* __restrict__ labels,
    const float* __restrict__ emb,
    float* __restrict__ part_loss,
    int* __restrict__ part_cnt)
{
    __shared__ float dist[2][NN];
    __shared__ int slbl[NN];
    __shared__ unsigned short plist[2][NN];
    __shared__ int pcnt[2];
    __shared__ float bloss;

    const int tid  = threadIdx.x;
    const int lane = tid & 63;
    const int wave = tid >> 6;
    const int s = lane & 7;       // column octet: f4 indices s, s+8, ..., s+120
    const int r = lane >> 3;      // row within 8-row group
    const int j0 = blockIdx.x * 2;

    slbl[tid] = labels[tid];
    if (tid < 2) pcnt[tid] = 0;
    if (tid == 0) bloss = 0.f;

    const float4* ef4 = (const float4*)emb;   // 128 float4 per row

    // ---- anchor fragments in registers: 2 rows x 16 f4 per lane ----
    float4 A0[16], A1[16];
    #pragma unroll
    for (int i = 0; i < 16; ++i) {
        A0[i] = ef4[(size_t)j0 * 128 + (i << 3) + s];
        A1[i] = ef4[(size_t)(j0 + 1) * 128 + (i << 3) + s];
    }

    // ---- distance rows: wave w owns rows [w*64, w*64+64), 8 at a time ----
    for (int g = 0; g < 8; ++g) {
        const int krow = (wave << 6) + (g << 3) + r;
        const float4* rowp = ef4 + (size_t)krow * 128 + s;
        float acc0 = 0.f, acc1 = 0.f;
        #pragma unroll
        for (int i = 0; i < 16; ++i) {
            const float4 e = rowp[i << 3];
            float t;
            t = A0[i].x - e.x; acc0 = fmaf(t, t, acc0);
            t = A0[i].y - e.y; acc0 = fmaf(t, t, acc0);
            t = A0[i].z - e.z; acc0 = fmaf(t, t, acc0);
            t = A0[i].w - e.w; acc0 = fmaf(t, t, acc0);
            t = A1[i].x - e.x; acc1 = fmaf(t, t, acc1);
            t = A1[i].y - e.y; acc1 = fmaf(t, t, acc1);
            t = A1[i].z - e.z; acc1 = fmaf(t, t, acc1);
            t = A1[i].w - e.w; acc1 = fmaf(t, t, acc1);
        }
        // reduce across the 8 sublanes (stays within each octet)
        acc0 += __shfl_xor(acc0, 1, 64); acc1 += __shfl_xor(acc1, 1, 64);
        acc0 += __shfl_xor(acc0, 2, 64); acc1 += __shfl_xor(acc1, 2, 64);
        acc0 += __shfl_xor(acc0, 4, 64); acc1 += __shfl_xor(acc1, 4, 64);
        if (s == 0) {
            // diagonal is exactly 0: row j0 loads the same words as A0 regs
            dist[0][krow] = sqrtf(acc0);
            dist[1][krow] = sqrtf(acc1);
        }
    }
    __syncthreads();

    // ---- positive lists ----
    #pragma unroll
    for (int rr = 0; rr < 2; ++rr) {
        const int j = j0 + rr;
        if (tid != j && slbl[tid] == slbl[j]) {
            const int idx = atomicAdd(&pcnt[rr], 1);
            plist[rr][idx] = (unsigned short)tid;
        }
    }
    __syncthreads();

    // ---- mining: one wave per positive pair ----
    float wloss = 0.f;
    for (int rr = 0; rr < 2; ++rr) {
        const int lbl = slbl[j0 + rr];
        const int np = pcnt[rr];
        for (int p = wave; p < np; p += NWAVES) {
            const int a = plist[rr][p];
            const float dpa = dist[rr][a];
            float vmin = 1e30f;   // min negative strictly farther than dpa
            float vmax = 0.f;     // fallback: max negative (0 if none)
            #pragma unroll
            for (int i = 0; i < NN / 64; ++i) {
                const int k = lane + (i << 6);
                const float dk = dist[rr][k];
                if (slbl[k] != lbl) {
                    vmax = fmaxf(vmax, dk);
                    if (dk > dpa) vmin = fminf(vmin, dk);
                }
            }
            #pragma unroll
            for (int o = 32; o > 0; o >>= 1) {
                vmin = fminf(vmin, __shfl_xor(vmin, o, 64));
                vmax = fmaxf(vmax, __shfl_xor(vmax, o, 64));
            }
            const float negd = (vmin < 1e29f) ? vmin : vmax;
            const float term = MARGIN_F + dpa - negd;
            if (lane == 0 && term > 0.f) wloss += term;
        }
    }
    if (lane == 0 && wloss != 0.f) atomicAdd(&bloss, wloss);
    __syncthreads();
    if (tid == 0) {
        part_loss[blockIdx.x] = bloss;                 // always written: no init needed
        part_cnt[blockIdx.x]  = pcnt[0] + pcnt[1];
    }
}

__global__ __launch_bounds__(256) void triplet_finalize(
    const float* __restrict__ part_loss,
    const int* __restrict__ part_cnt,
    float* __restrict__ out)
{
    __shared__ float sl[4];
    __shared__ int sc[4];
    const int tid = threadIdx.x;
    float L = part_loss[tid];
    int   c = part_cnt[tid];
    #pragma unroll
    for (int o = 32; o > 0; o >>= 1) {
        L += __shfl_xor(L, o, 64);
        c += __shfl_xor(c, o, 64);
    }
    if ((tid & 63) == 0) { sl[tid >> 6] = L; sc[tid >> 6] = c; }
    __syncthreads();
    if (tid == 0) {
        const float Ls = sl[0] + sl[1] + sl[2] + sl[3];
        const float cs = (float)(sc[0] + sc[1] + sc[2] + sc[3]);
        out[0] = Ls / (cs + 1e-8f);
    }
}

extern "C" void kernel_launch(void* const* d_in, const int* in_sizes, int n_in,
                              void* d_out, int out_size, void* d_ws, size_t ws_size,
                              hipStream_t stream) {
    const int* labels = (const int*)d_in[0];
    const float* emb  = (const float*)d_in[1];
    float* part_loss = (float*)d_ws;
    int*   part_cnt  = (int*)((char*)d_ws + 256 * sizeof(float));

    triplet_main<<<NN / 2, TPB, 0, stream>>>(labels, emb, part_loss, part_cnt);
    triplet_finalize<<<1, 256, 0, stream>>>(part_loss, part_cnt, (float*)d_out);
}

// Round 4
// 80.512 us; speedup vs baseline: 1.3055x; 1.3055x over previous
//
#include <hip/hip_runtime.h>
#include <math.h>

// TripletLoss semi-hard mining, N=512, D=512, C=64.
// v4: 3-kernel pipeline.
//   K0: row norms + bf16 hi/lo split of E + zero accums
//   K1: D[512][512] distance matrix via MFMA Gram tiles (hi*hi+hi*lo+lo*hi)
//   K2: per-row mining (verified v3 semantics) + last-block finalize
// For each ordered positive pair (j,a):
//   neg = min{ d[j][k] : lbl[k]!=lbl[j], d[j][k] > d[j][a] }
//         else max{ d[j][k] : lbl[k]!=lbl[j] } (0 if none)
//   loss += max(0, MARGIN + d[j][a] - neg);  out = loss / (numpos + 1e-8)

#define NN 512
#define DD 512
#define MARGIN_F 0.2f

typedef __attribute__((ext_vector_type(8))) short bf16x8;
typedef __attribute__((ext_vector_type(4))) float f32x4;

__device__ __forceinline__ unsigned short f2bf(float x){
    unsigned u = __float_as_uint(x);
    return (unsigned short)((u + 0x7FFFu + ((u >> 16) & 1u)) >> 16);   // RNE
}
__device__ __forceinline__ float bf2f(unsigned short h){
    return __uint_as_float(((unsigned)h) << 16);
}

// ---------------- K0: prep ----------------
__global__ __launch_bounds__(256) void k_prep(
    const float* __restrict__ emb,
    unsigned short* __restrict__ ehi,
    unsigned short* __restrict__ elo,
    float* __restrict__ norms,
    unsigned int* __restrict__ accums)   // [0]=loss(f32) [1]=cnt [2]=done
{
    const int tid = threadIdx.x, wave = tid >> 6, lane = tid & 63;
    const int j = blockIdx.x * 4 + wave;
    const float4* row = (const float4*)(emb + (size_t)j * DD);
    float acc = 0.f;
    #pragma unroll
    for (int i = 0; i < 2; ++i){
        const int f4i = lane + (i << 6);
        float4 v = row[f4i];
        acc = fmaf(v.x,v.x,acc); acc = fmaf(v.y,v.y,acc);
        acc = fmaf(v.z,v.z,acc); acc = fmaf(v.w,v.w,acc);
        ushort4 h, l;
        h.x = f2bf(v.x); l.x = f2bf(v.x - bf2f(h.x));
        h.y = f2bf(v.y); l.y = f2bf(v.y - bf2f(h.y));
        h.z = f2bf(v.z); l.z = f2bf(v.z - bf2f(h.z));
        h.w = f2bf(v.w); l.w = f2bf(v.w - bf2f(h.w));
        ((ushort4*)ehi)[(size_t)j * 128 + f4i] = h;
        ((ushort4*)elo)[(size_t)j * 128 + f4i] = l;
    }
    #pragma unroll
    for (int o = 32; o > 0; o >>= 1) acc += __shfl_xor(acc, o, 64);
    if (lane == 0) norms[j] = acc;
    if (blockIdx.x == 0 && tid < 3) accums[tid] = 0u;
}

// ---------------- K1: distance tiles ----------------
// grid (16,16); block (bi=blockIdx.y, bj=blockIdx.x) computes D tile
// rows bi*32.., cols bj*32.. ; 4 waves, one 16x16 MFMA quadrant each.
__global__ __launch_bounds__(256) void k_dist(
    const unsigned short* __restrict__ ehi,
    const unsigned short* __restrict__ elo,
    const float* __restrict__ norms,
    float* __restrict__ Dm)
{
    __shared__ short sh[4][32][136];   // 0=Ihi 1=Ilo 2=Jhi 3=Jlo; +8 pad
    const int tid = threadIdx.x;
    const int bi = blockIdx.y, bj = blockIdx.x;
    const int wave = tid >> 6, lane = tid & 63;
    const int rowb = (wave >> 1) * 16, colb = (wave & 1) * 16;
    const int fr = lane & 15;
    const int koff0 = (lane >> 4) * 8;

    f32x4 acc = {0.f, 0.f, 0.f, 0.f};

    for (int c = 0; c < 4; ++c){            // K-chunks of 128
        if (c) __syncthreads();
        #pragma unroll
        for (int u = 0; u < 8; ++u){
            const int idx = tid + (u << 8);          // 0..2047
            const int buf = idx >> 9;                // 0..3
            const int w = idx & 511;
            const int r = w >> 4, c8 = w & 15;
            const unsigned short* src = (buf & 1) ? elo : ehi;
            const int rowg = ((buf >> 1) ? bj : bi) * 32 + r;
            float4 v = ((const float4*)src)[(size_t)rowg * 64 + c * 16 + c8];
            *(float4*)(&sh[buf][r][c8 << 3]) = v;    // 16B-aligned (272B row stride)
        }
        __syncthreads();
        #pragma unroll
        for (int s = 0; s < 4; ++s){
            const int k = koff0 + (s << 5);
            bf16x8 ahi = *(const bf16x8*)(&sh[0][rowb + fr][k]);
            bf16x8 alo = *(const bf16x8*)(&sh[1][rowb + fr][k]);
            bf16x8 bhi = *(const bf16x8*)(&sh[2][colb + fr][k]);
            bf16x8 blo = *(const bf16x8*)(&sh[3][colb + fr][k]);
            acc = __builtin_amdgcn_mfma_f32_16x16x32_bf16(ahi, bhi, acc, 0, 0, 0);
            acc = __builtin_amdgcn_mfma_f32_16x16x32_bf16(ahi, blo, acc, 0, 0, 0);
            acc = __builtin_amdgcn_mfma_f32_16x16x32_bf16(alo, bhi, acc, 0, 0, 0);
        }
    }
    // epilogue: C/D layout col=lane&15, row=(lane>>4)*4+reg (m89-verified)
    const int colg = bj * 32 + colb + fr;
    const int rowg0 = bi * 32 + rowb + (lane >> 4) * 4;
    const float sc = norms[colg];
    #pragma unroll
    for (int reg = 0; reg < 4; ++reg){
        const int rowg = rowg0 + reg;
        const float d2 = norms[rowg] + sc - 2.f * acc[reg];
        Dm[(size_t)rowg * NN + colg] = sqrtf(fmaxf(d2, 0.f));
    }
}

// ---------------- K2: mining + finalize ----------------
__global__ __launch_bounds__(256) void k_mine(
    const int* __restrict__ labels,
    const float* __restrict__ Dm,
    float* __restrict__ accums,          // [0]=loss [1]=cnt(u32) [2]=done(u32)
    float* __restrict__ out,
    int nblocks)
{
    __shared__ int slbl[NN];
    __shared__ float drow[4][NN];
    __shared__ unsigned short plist[4][128];
    __shared__ int pcnt[4];

    const int tid = threadIdx.x, wave = tid >> 6, lane = tid & 63;
    const int j = blockIdx.x * 4 + wave;

    slbl[tid] = labels[tid];
    slbl[tid + 256] = labels[tid + 256];
    if (tid < 4) pcnt[tid] = 0;
    __syncthreads();

    // distance row j: 8 values per lane in registers + LDS copy for dpa lookups
    const float4* rp = (const float4*)(Dm + (size_t)j * NN);
    const float4 va = rp[lane * 2], vb = rp[lane * 2 + 1];
    *(float4*)(&drow[wave][lane * 8]) = va;
    *(float4*)(&drow[wave][lane * 8 + 4]) = vb;
    float d[8] = {va.x, va.y, va.z, va.w, vb.x, vb.y, vb.z, vb.w};
    const int lj = slbl[j];
    int lb[8];
    #pragma unroll
    for (int m = 0; m < 8; ++m) lb[m] = slbl[lane * 8 + m];

    // positive list (wave-local LDS; in-order per-wave DS ops)
    #pragma unroll
    for (int m = 0; m < 8; ++m){
        const int k = lane * 8 + m;
        if (k != j && lb[m] == lj){
            const int ix = atomicAdd(&pcnt[wave], 1);
            plist[wave][ix] = (unsigned short)k;
        }
    }
    // max over negatives: dpa-independent, reduce once per row
    float vmaxl = 0.f;
    #pragma unroll
    for (int m = 0; m < 8; ++m) if (lb[m] != lj) vmaxl = fmaxf(vmaxl, d[m]);
    #pragma unroll
    for (int o = 32; o > 0; o >>= 1) vmaxl = fmaxf(vmaxl, __shfl_xor(vmaxl, o, 64));

    const int np = pcnt[wave];
    float wloss = 0.f;
    for (int p = 0; p < np; ++p){
        const int a = plist[wave][p];
        const float dpa = drow[wave][a];
        float vm = 1e30f;   // min negative strictly farther than dpa
        #pragma unroll
        for (int m = 0; m < 8; ++m){
            const bool cnd = (lb[m] != lj) && (d[m] > dpa);
            vm = cnd ? fminf(vm, d[m]) : vm;
        }
        #pragma unroll
        for (int o = 32; o > 0; o >>= 1) vm = fminf(vm, __shfl_xor(vm, o, 64));
        const float neg = (vm < 1e29f) ? vm : vmaxl;
        const float term = MARGIN_F + dpa - neg;
        if (lane == 0 && term > 0.f) wloss += term;
    }
    if (lane == 0){
        if (wloss != 0.f) atomicAdd(&accums[0], wloss);
        if (np) atomicAdd((unsigned int*)&accums[1], (unsigned int)np);
    }
    __syncthreads();
    if (tid == 0){
        __threadfence();
        const unsigned old = atomicAdd((unsigned int*)&accums[2], 1u);
        if (old == (unsigned)(nblocks - 1)){
            const float L = atomicAdd(&accums[0], 0.f);
            const unsigned C = atomicAdd((unsigned int*)&accums[1], 0u);
            out[0] = L / ((float)C + 1e-8f);
        }
    }
}

extern "C" void kernel_launch(void* const* d_in, const int* in_sizes, int n_in,
                              void* d_out, int out_size, void* d_ws, size_t ws_size,
                              hipStream_t stream) {
    (void)in_sizes; (void)n_in; (void)out_size; (void)ws_size;
    const int* labels = (const int*)d_in[0];
    const float* emb  = (const float*)d_in[1];
    char* ws = (char*)d_ws;
    float*          Dm     = (float*)ws;                                   // 1 MB
    unsigned short* ehi    = (unsigned short*)(ws + (1u << 20));           // 512 KB
    unsigned short* elo    = (unsigned short*)(ws + (1u << 20) + (1u << 19));
    float*          norms  = (float*)(ws + (1u << 21));                    // 2 KB
    unsigned int*   accums = (unsigned int*)(ws + (1u << 21) + 4096u);

    k_prep<<<128, 256, 0, stream>>>(emb, ehi, elo, norms, accums);
    k_dist<<<dim3(16, 16), 256, 0, stream>>>(ehi, elo, norms, Dm);
    k_mine<<<128, 256, 0, stream>>>(labels, Dm, (float*)accums, (float*)d_out, 128);
}